// Round 3
// baseline (180.022 us; speedup 1.0000x reference)
//
#include <hip/hip_runtime.h>

// Problem constants: n_class=32, n_support=16, n_query=16, D=1024;
// query rows Q = 512. Output (512, 32, 1024) fp32.
constexpr int NC = 32, NS = 16, NQ = 512, D = 1024;
constexpr int QPB = 8;     // queries per block = 4 waves x 2 queries/wave

// 1/(exp2(t0)+1) + 1/(exp2(t1)+1) with ONE rcp:
// x=exp2(t0)+1, y=exp2(t1)+1  ->  (x+y) / (x*y).
// No clamp needed: |t| = K*|s*q| <= ~75 < 127 for this data (|elem| < ~5.1),
// so exp2 never overflows individually and x+y stays finite. If x*y
// overflows to inf, rcp gives 0 and the pair contributes 0 (truth ~2^-100):
// numerically correct, and NaN is impossible (x+y < inf always).
__device__ __forceinline__ float pair_term(float t0, float t1) {
    float x = __builtin_amdgcn_exp2f(t0) + 1.f;
    float y = __builtin_amdgcn_exp2f(t1) + 1.f;
    return (x + y) * __builtin_amdgcn_rcpf(x * y);
}

// No LDS at all: support[c] (64 KB) is L2-resident (2 MB total over 32
// classes) and re-read through L1/L2. This removes all staging writes,
// all 6 __syncthreads, the restage pass, and all LDS bank conflicts.
// launch_bounds(256,2): VGPR cap 128 -> no spills (live ~100).
__global__ __launch_bounds__(256, 2)
void proto_attn_kernel(const float* __restrict__ data, float* __restrict__ out) {
    const int c    = blockIdx.x;   // class
    const int qt   = blockIdx.y;   // query tile
    const int tid  = threadIdx.x;
    const int wave = tid >> 6;
    const int lane = tid & 63;

    // support[c] as float4 rows: row s = sg[s*256 + (0..255)]
    const float4* sg = reinterpret_cast<const float4*>(data + (size_t)c * NS * D);

    // ---- load this wave's two query rows, pre-scaled by K = 2*log2(e) ----
    // tanh(x) = 1 - 2/(exp2(K*x)+1)
    const float K = 2.88539008177792681472f;
    const int q0 = qt * QPB + wave * 2;
    const float4* qg0 = reinterpret_cast<const float4*>(data + (size_t)(NC * NS + q0) * D);
    const float4* qg1 = qg0 + 256;   // next query row
    float4 qa[4], qb[4];
    #pragma unroll
    for (int j = 0; j < 4; ++j) {
        float4 t0 = qg0[lane + 64 * j];
        float4 t1 = qg1[lane + 64 * j];
        qa[j] = make_float4(t0.x * K, t0.y * K, t0.z * K, t0.w * K);
        qb[j] = make_float4(t1.x * K, t1.y * K, t1.z * K, t1.w * K);
    }

    // ---- scores: sc[q][s] = D - 2 * sum_d 1/(exp2(K*s*q)+1) ----
    float sc0[NS], sc1[NS];
    #pragma unroll
    for (int s = 0; s < NS; ++s) {
        float u0 = 0.f, v0 = 0.f, u1 = 0.f, v1 = 0.f;   // independent chains
        #pragma unroll
        for (int j = 0; j < 4; ++j) {
            float4 sv = sg[s * 256 + lane + 64 * j];
            float4 qA = qa[j], qB = qb[j];
            u0 += pair_term(sv.x * qA.x, sv.y * qA.y);
            v0 += pair_term(sv.z * qA.z, sv.w * qA.w);
            u1 += pair_term(sv.x * qB.x, sv.y * qB.y);
            v1 += pair_term(sv.z * qB.z, sv.w * qB.w);
        }
        sc0[s] = u0 + v0;
        sc1[s] = u1 + v1;
    }

    // ---- wave64 butterfly reduction over d ----
    #pragma unroll
    for (int s = 0; s < NS; ++s) {
        float r0 = sc0[s], r1 = sc1[s];
        #pragma unroll
        for (int m = 32; m >= 1; m >>= 1) {
            r0 += __shfl_xor(r0, m, 64);
            r1 += __shfl_xor(r1, m, 64);
        }
        sc0[s] = (float)D - 2.f * r0;
        sc1[s] = (float)D - 2.f * r1;
    }

    // ---- softmax over s (16 values, replicated in every lane) ----
    const float L2E = 1.44269504088896340736f;
    float m0 = sc0[0], m1 = sc1[0];
    #pragma unroll
    for (int s = 1; s < NS; ++s) { m0 = fmaxf(m0, sc0[s]); m1 = fmaxf(m1, sc1[s]); }
    float sum0 = 0.f, sum1 = 0.f;
    #pragma unroll
    for (int s = 0; s < NS; ++s) {
        sc0[s] = __builtin_amdgcn_exp2f((sc0[s] - m0) * L2E);
        sc1[s] = __builtin_amdgcn_exp2f((sc1[s] - m1) * L2E);
        sum0 += sc0[s];
        sum1 += sc1[s];
    }
    const float inv0 = __builtin_amdgcn_rcpf(sum0);
    const float inv1 = __builtin_amdgcn_rcpf(sum1);
    #pragma unroll
    for (int s = 0; s < NS; ++s) { sc0[s] *= inv0; sc1[s] *= inv1; }

    // ---- proto: out[q,c,:] = sum_s att[s] * support[c,s,:] (from global) ----
    float4 o0[4], o1[4];
    #pragma unroll
    for (int j = 0; j < 4; ++j) {
        o0[j] = make_float4(0.f, 0.f, 0.f, 0.f);
        o1[j] = make_float4(0.f, 0.f, 0.f, 0.f);
    }
    #pragma unroll
    for (int s = 0; s < NS; ++s) {
        const float a0 = sc0[s], a1 = sc1[s];
        #pragma unroll
        for (int j = 0; j < 4; ++j) {
            float4 sv = sg[s * 256 + lane + 64 * j];
            o0[j].x += a0 * sv.x; o0[j].y += a0 * sv.y;
            o0[j].z += a0 * sv.z; o0[j].w += a0 * sv.w;
            o1[j].x += a1 * sv.x; o1[j].y += a1 * sv.y;
            o1[j].z += a1 * sv.z; o1[j].w += a1 * sv.w;
        }
    }
    float4* og0 = reinterpret_cast<float4*>(out + ((size_t)q0 * NC + c) * D);
    float4* og1 = reinterpret_cast<float4*>(out + ((size_t)(q0 + 1) * NC + c) * D);
    #pragma unroll
    for (int j = 0; j < 4; ++j) {
        og0[lane + 64 * j] = o0[j];
        og1[lane + 64 * j] = o1[j];
    }
}

extern "C" void kernel_launch(void* const* d_in, const int* in_sizes, int n_in,
                              void* d_out, int out_size, void* d_ws, size_t ws_size,
                              hipStream_t stream) {
    (void)in_sizes; (void)n_in; (void)out_size; (void)d_ws; (void)ws_size;
    const float* data = (const float*)d_in[0];
    float* out = (float*)d_out;
    dim3 grid(NC, NQ / QPB);   // 32 classes x 64 query tiles = 2048 blocks
    proto_attn_kernel<<<grid, dim3(256), 0, stream>>>(data, out);
}

// Round 5
// 155.608 us; speedup vs baseline: 1.1569x; 1.1569x over previous
//
#include <hip/hip_runtime.h>

// Problem constants: n_class=32, n_support=16, n_query=16, D=1024;
// query rows Q = 512. Output (512, 32, 1024) fp32.
constexpr int NC = 32, NS = 16, NQ = 512, D = 1024;
constexpr int QPB = 8;     // queries per block = 4 waves x 2 queries/wave
constexpr int F4H = 128;   // float4 per support row per d-half (512 floats)

// native clang vector for nontemporal builtins (HIP float4 is a class type,
// which __builtin_nontemporal_store rejects)
typedef float v4f __attribute__((ext_vector_type(4)));

// 1/(exp2(t0)+1) + 1/(exp2(t1)+1) with ONE rcp:
// x=exp2(t0)+1, y=exp2(t1)+1  ->  (x+y)/(x*y).
// No clamp needed (validated round 3: passed, absmax unchanged): individual
// exp2 can't overflow for this data; if x*y -> inf, rcp -> 0 and the pair
// contributes 0 where truth ~2^-100; x+y stays finite so no NaN.
__device__ __forceinline__ float pair_term(float t0, float t1) {
    float x = __builtin_amdgcn_exp2f(t0) + 1.f;
    float y = __builtin_amdgcn_exp2f(t1) + 1.f;
    return (x + y) * __builtin_amdgcn_rcpf(x * y);
}

// launch_bounds(256,2): VGPR cap 128 (k=4 capped at 64 and spilled ~37/lane
// in round 1 -> catastrophic). Peak live here ~100 regs -> no spills.
__global__ __launch_bounds__(256, 2)
void proto_attn_kernel(const float* __restrict__ data, float* __restrict__ out) {
    const int c    = blockIdx.x;   // class
    const int qt   = blockIdx.y;   // query tile
    const int tid  = threadIdx.x;
    const int wave = tid >> 6;
    const int lane = tid & 63;

    // One d-half of support[c]: 16 rows x 512 floats = 32 KB.
    __shared__ float4 sup4[NS * F4H];

    const float4* sg = reinterpret_cast<const float4*>(data + (size_t)c * NS * D);
    const float K = 2.88539008177792681472f;   // 2*log2(e); tanh(x)=1-2/(exp2(K x)+1)
    const int q0 = qt * QPB + wave * 2;
    const float4* qg0 = reinterpret_cast<const float4*>(data + (size_t)(NC * NS + q0) * D);
    const float4* qg1 = qg0 + 256;   // next query row

    // ---- T14 async-stage: issue global loads early, ds_write late. ----
    // prologue: stage d-half 0 (latency partially overlapped with q loads below)
    float4 pre[8];
    #pragma unroll
    for (int i = 0; i < 8; ++i) {
        int idx = tid + 256 * i;
        pre[i] = sg[((idx >> 7) << 8) + (idx & 127)];
    }
    #pragma unroll
    for (int i = 0; i < 8; ++i) sup4[tid + 256 * i] = pre[i];
    __syncthreads();

    // issue d-half-1 loads NOW; they retire under score-h0 (~3000 cy of compute)
    #pragma unroll
    for (int i = 0; i < 8; ++i) {
        int idx = tid + 256 * i;
        pre[i] = sg[((idx >> 7) << 8) + 128 + (idx & 127)];
    }

    // queries, half 0 (cols j=0,1), scaled by K. Reloaded per half (L1-hot)
    // to keep peak VGPR below the 128 cap while pre[] (32 regs) is in flight.
    float4 qa[2], qb[2];
    #pragma unroll
    for (int j = 0; j < 2; ++j) {
        float4 t0 = qg0[lane + 64 * j];
        float4 t1 = qg1[lane + 64 * j];
        qa[j] = make_float4(t0.x * K, t0.y * K, t0.z * K, t0.w * K);
        qb[j] = make_float4(t1.x * K, t1.y * K, t1.z * K, t1.w * K);
    }

    // ---- partial scores over d-half 0 ----
    float sc0[NS], sc1[NS];
    #pragma unroll
    for (int s = 0; s < NS; ++s) {
        float u0 = 0.f, v0 = 0.f, u1 = 0.f, v1 = 0.f;   // independent chains
        #pragma unroll
        for (int jj = 0; jj < 2; ++jj) {
            float4 sv = sup4[s * F4H + lane + 64 * jj];
            u0 += pair_term(sv.x * qa[jj].x, sv.y * qa[jj].y);
            v0 += pair_term(sv.z * qa[jj].z, sv.w * qa[jj].w);
            u1 += pair_term(sv.x * qb[jj].x, sv.y * qb[jj].y);
            v1 += pair_term(sv.z * qb[jj].z, sv.w * qb[jj].w);
        }
        sc0[s] = u0 + v0;
        sc1[s] = u1 + v1;
    }
    __syncthreads();   // all waves done reading half 0

    // write the (already-arrived) half-1 data; barrier waits only on ds_write
    #pragma unroll
    for (int i = 0; i < 8; ++i) sup4[tid + 256 * i] = pre[i];
    __syncthreads();

    // queries, half 1 (cols j=2,3)
    #pragma unroll
    for (int j = 0; j < 2; ++j) {
        float4 t0 = qg0[lane + 64 * (2 + j)];
        float4 t1 = qg1[lane + 64 * (2 + j)];
        qa[j] = make_float4(t0.x * K, t0.y * K, t0.z * K, t0.w * K);
        qb[j] = make_float4(t1.x * K, t1.y * K, t1.z * K, t1.w * K);
    }

    // ---- finish scores over d-half 1 ----
    #pragma unroll
    for (int s = 0; s < NS; ++s) {
        float u0 = 0.f, v0 = 0.f, u1 = 0.f, v1 = 0.f;
        #pragma unroll
        for (int jj = 0; jj < 2; ++jj) {
            float4 sv = sup4[s * F4H + lane + 64 * jj];
            u0 += pair_term(sv.x * qa[jj].x, sv.y * qa[jj].y);
            v0 += pair_term(sv.z * qa[jj].z, sv.w * qa[jj].w);
            u1 += pair_term(sv.x * qb[jj].x, sv.y * qb[jj].y);
            v1 += pair_term(sv.z * qb[jj].z, sv.w * qb[jj].w);
        }
        sc0[s] += u0 + v0;
        sc1[s] += u1 + v1;
    }

    // issue restage (half-0) loads NOW — L2-hot; they retire under the
    // reduction + softmax + proto-h1 compute below.
    #pragma unroll
    for (int i = 0; i < 8; ++i) {
        int idx = tid + 256 * i;
        pre[i] = sg[((idx >> 7) << 8) + (idx & 127)];
    }

    // ---- wave64 butterfly reduction: sc[q][s] = D - 2*sum_d 1/(exp2+1) ----
    #pragma unroll
    for (int s = 0; s < NS; ++s) {
        float r0 = sc0[s], r1 = sc1[s];
        #pragma unroll
        for (int m = 32; m >= 1; m >>= 1) {
            r0 += __shfl_xor(r0, m, 64);
            r1 += __shfl_xor(r1, m, 64);
        }
        sc0[s] = (float)D - 2.f * r0;
        sc1[s] = (float)D - 2.f * r1;
    }

    // ---- softmax over s (16 values, replicated in every lane) ----
    const float L2E = 1.44269504088896340736f;
    float m0 = sc0[0], m1 = sc1[0];
    #pragma unroll
    for (int s = 1; s < NS; ++s) { m0 = fmaxf(m0, sc0[s]); m1 = fmaxf(m1, sc1[s]); }
    float sum0 = 0.f, sum1 = 0.f;
    #pragma unroll
    for (int s = 0; s < NS; ++s) {
        sc0[s] = __builtin_amdgcn_exp2f((sc0[s] - m0) * L2E);
        sc1[s] = __builtin_amdgcn_exp2f((sc1[s] - m1) * L2E);
        sum0 += sc0[s];
        sum1 += sc1[s];
    }
    const float inv0 = __builtin_amdgcn_rcpf(sum0);
    const float inv1 = __builtin_amdgcn_rcpf(sum1);
    #pragma unroll
    for (int s = 0; s < NS; ++s) { sc0[s] *= inv0; sc1[s] *= inv1; }

    float* orow0 = out + ((size_t)q0 * NC + c) * D;
    float* orow1 = orow0 + (size_t)NC * D;

    // ---- proto over d-half 1 (currently staged), nontemporal store ----
    // nt stores keep the 64 MB output stream from evicting L2-hot support.
    {
        float4 o0[2], o1[2];
        o0[0] = o0[1] = o1[0] = o1[1] = make_float4(0.f, 0.f, 0.f, 0.f);
        #pragma unroll
        for (int s = 0; s < NS; ++s) {
            const float a0 = sc0[s], a1 = sc1[s];
            #pragma unroll
            for (int jj = 0; jj < 2; ++jj) {
                float4 sv = sup4[s * F4H + lane + 64 * jj];
                o0[jj].x += a0 * sv.x; o0[jj].y += a0 * sv.y;
                o0[jj].z += a0 * sv.z; o0[jj].w += a0 * sv.w;
                o1[jj].x += a1 * sv.x; o1[jj].y += a1 * sv.y;
                o1[jj].z += a1 * sv.z; o1[jj].w += a1 * sv.w;
            }
        }
        v4f* og0 = reinterpret_cast<v4f*>(orow0) + 128;
        v4f* og1 = reinterpret_cast<v4f*>(orow1) + 128;
        #pragma unroll
        for (int jj = 0; jj < 2; ++jj) {
            __builtin_nontemporal_store(*reinterpret_cast<v4f*>(&o0[jj]), og0 + lane + 64 * jj);
            __builtin_nontemporal_store(*reinterpret_cast<v4f*>(&o1[jj]), og1 + lane + 64 * jj);
        }
    }
    __syncthreads();   // all waves done reading half 1

    // restage half 0 from regs (loads long since arrived), proto, store
    #pragma unroll
    for (int i = 0; i < 8; ++i) sup4[tid + 256 * i] = pre[i];
    __syncthreads();
    {
        float4 o0[2], o1[2];
        o0[0] = o0[1] = o1[0] = o1[1] = make_float4(0.f, 0.f, 0.f, 0.f);
        #pragma unroll
        for (int s = 0; s < NS; ++s) {
            const float a0 = sc0[s], a1 = sc1[s];
            #pragma unroll
            for (int jj = 0; jj < 2; ++jj) {
                float4 sv = sup4[s * F4H + lane + 64 * jj];
                o0[jj].x += a0 * sv.x; o0[jj].y += a0 * sv.y;
                o0[jj].z += a0 * sv.z; o0[jj].w += a0 * sv.w;
                o1[jj].x += a1 * sv.x; o1[jj].y += a1 * sv.y;
                o1[jj].z += a1 * sv.z; o1[jj].w += a1 * sv.w;
            }
        }
        v4f* og0 = reinterpret_cast<v4f*>(orow0);
        v4f* og1 = reinterpret_cast<v4f*>(orow1);
        #pragma unroll
        for (int jj = 0; jj < 2; ++jj) {
            __builtin_nontemporal_store(*reinterpret_cast<v4f*>(&o0[jj]), og0 + lane + 64 * jj);
            __builtin_nontemporal_store(*reinterpret_cast<v4f*>(&o1[jj]), og1 + lane + 64 * jj);
        }
    }
}

extern "C" void kernel_launch(void* const* d_in, const int* in_sizes, int n_in,
                              void* d_out, int out_size, void* d_ws, size_t ws_size,
                              hipStream_t stream) {
    (void)in_sizes; (void)n_in; (void)out_size; (void)d_ws; (void)ws_size;
    const float* data = (const float*)d_in[0];
    float* out = (float*)d_out;
    dim3 grid(NC, NQ / QPB);   // 32 classes x 64 query tiles = 2048 blocks
    proto_attn_kernel<<<grid, dim3(256), 0, stream>>>(data, out);
}

// Round 6
// 151.407 us; speedup vs baseline: 1.1890x; 1.0277x over previous
//
#include <hip/hip_runtime.h>

// Problem constants: n_class=32, n_support=16, n_query=16, D=1024;
// query rows Q = 512. Output (512, 32, 1024) fp32.
constexpr int NC = 32, NS = 16, NQ = 512, D = 1024;
constexpr int QPB = 8;     // queries per tile = 4 waves x 2 queries/wave
constexpr int TPB = 2;     // query tiles per block (same class -> shared staging)
constexpr int F4Q = 64;    // float4 per support row per d-quarter (256 floats)

// native clang vector for nontemporal builtins
typedef float v4f __attribute__((ext_vector_type(4)));

// 1/(exp2(t0)+1) + 1/(exp2(t1)+1) with ONE rcp: (x+y)/(x*y).
// No clamp (validated rounds 3/5: pass, absmax unchanged).
__device__ __forceinline__ float pair_term(float t0, float t1) {
    float x = __builtin_amdgcn_exp2f(t0) + 1.f;
    float y = __builtin_amdgcn_exp2f(t1) + 1.f;
    return (x + y) * __builtin_amdgcn_rcpf(x * y);
}

// launch_bounds(256,2): VGPR cap 128. Rounds 1 & 5 proved caps below the
// live set spill catastrophically (scratch traffic in WRITE_SIZE). In-flight
// staging here is only pre[4]=16 regs across ONE short phase.
__global__ __launch_bounds__(256, 2)
void proto_attn_kernel(const float* __restrict__ data, float* __restrict__ out) {
    const int c    = blockIdx.x & 31;    // class
    const int pr   = blockIdx.x >> 5;    // tile-pair 0..31
    const int tid  = threadIdx.x;
    const int wave = tid >> 6;
    const int lane = tid & 63;

    // Double-buffered d-quarter of support[c]: 2 x (16 rows x 256 floats) = 32 KB.
    // grid=1024 -> exactly 4 blocks/CU, all resident (128 KB LDS/CU): one
    // generation, no block churn.
    __shared__ float4 buf[2][NS * F4Q];

    const float4* sg    = reinterpret_cast<const float4*>(data + (size_t)c * NS * D);
    const float4* qbase = reinterpret_cast<const float4*>(data + (size_t)NC * NS * D);
    const float K = 2.88539008177792681472f;   // 2*log2(e); tanh(x)=1-2/(exp2(Kx)+1)

    float4 pre[4];   // in-flight staging (16 regs, one phase lifetime)
    auto issue = [&](int p) {        // global loads for quarter p (L2-hot)
        #pragma unroll
        for (int i = 0; i < 4; ++i) {
            int idx = tid + 256 * i;                      // row=idx>>6, col=idx&63
            pre[i] = sg[((idx >> 6) << 8) + (p << 6) + (idx & 63)];
        }
    };
    auto commit = [&](int b) {       // ds_write into buffer b
        #pragma unroll
        for (int i = 0; i < 4; ++i) buf[b][tid + 256 * i] = pre[i];
    };

    auto reduce_softmax = [&](float (&s0)[NS], float (&s1)[NS]) {
        #pragma unroll
        for (int s = 0; s < NS; ++s) {
            float r0 = s0[s], r1 = s1[s];
            #pragma unroll
            for (int m = 32; m >= 1; m >>= 1) {
                r0 += __shfl_xor(r0, m, 64);
                r1 += __shfl_xor(r1, m, 64);
            }
            s0[s] = (float)D - 2.f * r0;
            s1[s] = (float)D - 2.f * r1;
        }
        const float L2E = 1.44269504088896340736f;
        float m0 = s0[0], m1 = s1[0];
        #pragma unroll
        for (int s = 1; s < NS; ++s) { m0 = fmaxf(m0, s0[s]); m1 = fmaxf(m1, s1[s]); }
        float sum0 = 0.f, sum1 = 0.f;
        #pragma unroll
        for (int s = 0; s < NS; ++s) {
            s0[s] = __builtin_amdgcn_exp2f((s0[s] - m0) * L2E);
            s1[s] = __builtin_amdgcn_exp2f((s1[s] - m1) * L2E);
            sum0 += s0[s]; sum1 += s1[s];
        }
        float i0 = __builtin_amdgcn_rcpf(sum0), i1 = __builtin_amdgcn_rcpf(sum1);
        #pragma unroll
        for (int s = 0; s < NS; ++s) { s0[s] *= i0; s1[s] *= i1; }
    };

    auto nt_store4 = [](float* p, float4 v) {
        __builtin_nontemporal_store(*reinterpret_cast<v4f*>(&v),
                                    reinterpret_cast<v4f*>(p));
    };

    // query rows for the two tiles handled by this block
    const int t0q = (pr * TPB + 0) * QPB + wave * 2;
    const int t1q = (pr * TPB + 1) * QPB + wave * 2;
    const float4* t0g0 = qbase + (size_t)t0q * 256;
    const float4* t0g1 = t0g0 + 256;
    const float4* t1g0 = qbase + (size_t)t1q * 256;
    const float4* t1g1 = t1g0 + 256;

    float* o00 = out + ((size_t)t0q * NC + c) * D;   // tile0, query row 0
    float* o01 = o00 + (size_t)NC * D;               // tile0, query row 1
    float* o10 = out + ((size_t)t1q * NC + c) * D;   // tile1
    float* o11 = o10 + (size_t)NC * D;

    // ---- prologue: stage quarter 0 -> buf0 ----
    issue(0);
    commit(0);
    __syncthreads();

    // ================= score tile0 : quarters 0..3 =================
    // Phase invariant: phase reads buf[p&1], writes next quarter into the
    // OTHER buffer (last read one phase ago, protected by previous barrier);
    // one barrier per phase.
    float sa0[NS], sa1[NS];
    #pragma unroll
    for (int s = 0; s < NS; ++s) { sa0[s] = 0.f; sa1[s] = 0.f; }

    #pragma unroll
    for (int p = 0; p < 4; ++p) {
        issue((p + 1) & 3);                         // wraps to q0 for fused loop
        float4 qa = t0g0[(p << 6) + lane];
        float4 qb = t0g1[(p << 6) + lane];
        qa.x *= K; qa.y *= K; qa.z *= K; qa.w *= K;
        qb.x *= K; qb.y *= K; qb.z *= K; qb.w *= K;
        const float4* B = buf[p & 1];
        #pragma unroll
        for (int s = 0; s < NS; ++s) {
            float4 sv = B[(s << 6) + lane];
            sa0[s] += pair_term(sv.x * qa.x, sv.y * qa.y)
                    + pair_term(sv.z * qa.z, sv.w * qa.w);
            sa1[s] += pair_term(sv.x * qb.x, sv.y * qb.y)
                    + pair_term(sv.z * qb.z, sv.w * qb.w);
        }
        commit((p + 1) & 1);
        __syncthreads();
    }

    reduce_softmax(sa0, sa1);    // sa = att(tile0), replicated per lane

    // ====== fused: proto(tile0) + score(tile1), quarters 0..3 ======
    // Proto's independent FMAs fill full-rate issue slots while score's
    // mul->exp2->add->rcp chains occupy the trans pipe; each staged quarter
    // feeds both workloads.
    float sb0[NS], sb1[NS];
    #pragma unroll
    for (int s = 0; s < NS; ++s) { sb0[s] = 0.f; sb1[s] = 0.f; }

    #pragma unroll
    for (int p = 0; p < 4; ++p) {
        issue((p + 1) & 3);
        float4 qa = t1g0[(p << 6) + lane];
        float4 qb = t1g1[(p << 6) + lane];
        qa.x *= K; qa.y *= K; qa.z *= K; qa.w *= K;
        qb.x *= K; qb.y *= K; qb.z *= K; qb.w *= K;
        const float4* B = buf[p & 1];
        float4 o0 = make_float4(0.f, 0.f, 0.f, 0.f);
        float4 o1 = make_float4(0.f, 0.f, 0.f, 0.f);
        #pragma unroll
        for (int s = 0; s < NS; ++s) {
            float4 sv = B[(s << 6) + lane];
            const float a0 = sa0[s], a1 = sa1[s];
            o0.x += a0 * sv.x; o0.y += a0 * sv.y; o0.z += a0 * sv.z; o0.w += a0 * sv.w;
            o1.x += a1 * sv.x; o1.y += a1 * sv.y; o1.z += a1 * sv.z; o1.w += a1 * sv.w;
            sb0[s] += pair_term(sv.x * qa.x, sv.y * qa.y)
                    + pair_term(sv.z * qa.z, sv.w * qa.w);
            sb1[s] += pair_term(sv.x * qb.x, sv.y * qb.y)
                    + pair_term(sv.z * qb.z, sv.w * qb.w);
        }
        nt_store4(o00 + (p << 8) + 4 * lane, o0);
        nt_store4(o01 + (p << 8) + 4 * lane, o1);
        commit((p + 1) & 1);
        __syncthreads();
    }

    reduce_softmax(sb0, sb1);    // att(tile1)

    // ================= proto tile1 : quarters 0..3 =================
    #pragma unroll
    for (int p = 0; p < 4; ++p) {
        if (p < 3) issue(p + 1);
        const float4* B = buf[p & 1];
        float4 o0 = make_float4(0.f, 0.f, 0.f, 0.f);
        float4 o1 = make_float4(0.f, 0.f, 0.f, 0.f);
        #pragma unroll
        for (int s = 0; s < NS; ++s) {
            float4 sv = B[(s << 6) + lane];
            const float a0 = sb0[s], a1 = sb1[s];
            o0.x += a0 * sv.x; o0.y += a0 * sv.y; o0.z += a0 * sv.z; o0.w += a0 * sv.w;
            o1.x += a1 * sv.x; o1.y += a1 * sv.y; o1.z += a1 * sv.z; o1.w += a1 * sv.w;
        }
        nt_store4(o10 + (p << 8) + 4 * lane, o0);
        nt_store4(o11 + (p << 8) + 4 * lane, o1);
        if (p < 3) {
            commit((p + 1) & 1);
            __syncthreads();
        }
    }
}

extern "C" void kernel_launch(void* const* d_in, const int* in_sizes, int n_in,
                              void* d_out, int out_size, void* d_ws, size_t ws_size,
                              hipStream_t stream) {
    (void)in_sizes; (void)n_in; (void)out_size; (void)d_ws; (void)ws_size;
    const float* data = (const float*)d_in[0];
    float* out = (float*)d_out;
    // 32 classes x 32 tile-pairs = 1024 blocks = exactly 4 per CU (one generation)
    proto_attn_kernel<<<dim3(NC * (NQ / QPB / TPB)), dim3(256), 0, stream>>>(data, out);
}

// Round 7
// 130.193 us; speedup vs baseline: 1.3827x; 1.1629x over previous
//
#include <hip/hip_runtime.h>

// Problem constants: n_class=32, n_support=16, n_query=16, D=1024;
// query rows Q = 512. Output (512, 32, 1024) fp32.
constexpr int NC = 32, NS = 16, NQ = 512, D = 1024;
constexpr int QPB = 8;     // queries per block = 4 waves x 2 queries/wave
constexpr int F4H = 128;   // float4 per support row per d-half (512 floats)

// clang ext-vectors -> VOP3P packed fp32 (v_pk_fma_f32 etc., full-rate 2xf32)
typedef float v2f __attribute__((ext_vector_type(2)));
typedef float v4f __attribute__((ext_vector_type(4)));

// Packed quad term: given t01={t0,t1}, t23={t2,t3} (pre-multiplied by K*q),
// returns {f(t0)+f(t2), f(t1)+f(t3)} where f(t)=1/(exp2(t)+1), using 2 rcp
// for 4 elements and packed full-rate ops throughout:
//   A=exp2(t01)+1, B=exp2(t23)+1 -> pairs (A.x,B.x),(A.y,B.y):
//   f pair sum = (A+B) * rcp(A*B)   [pk_add, pk_mul, 2x rcp, pk_mul]
// No clamp (validated rounds 3/5/6: pass, absmax unchanged): exp2 can't
// overflow individually; if A*B -> inf, rcp -> 0, contribution 0 (truth
// ~2^-100), and A+B stays finite so no NaN.
__device__ __forceinline__ v2f quad_term(v2f t01, v2f t23) {
    v2f A, B;
    A.x = __builtin_amdgcn_exp2f(t01.x);
    A.y = __builtin_amdgcn_exp2f(t01.y);
    B.x = __builtin_amdgcn_exp2f(t23.x);
    B.y = __builtin_amdgcn_exp2f(t23.y);
    A += 1.f;                  // v_pk_add
    B += 1.f;                  // v_pk_add
    v2f prod = A * B;          // v_pk_mul
    v2f sum  = A + B;          // v_pk_add
    v2f r;
    r.x = __builtin_amdgcn_rcpf(prod.x);
    r.y = __builtin_amdgcn_rcpf(prod.y);
    return sum * r;            // v_pk_mul (accumulate fuses to v_pk_fma)
}

// launch_bounds(256,2): VGPR cap 128. Caps below the live set (rounds 1/5)
// or live sets above the cap (round 6 fusion) spill catastrophically —
// watch WRITE_SIZE == 65536 KB as the no-spill tripwire.
__global__ __launch_bounds__(256, 2)
void proto_attn_kernel(const float* __restrict__ data, float* __restrict__ out) {
    const int c    = blockIdx.x;   // class
    const int qt   = blockIdx.y;   // query tile
    const int tid  = threadIdx.x;
    const int wave = tid >> 6;
    const int lane = tid & 63;

    // One d-half of support[c]: 16 rows x 512 floats = 32 KB.
    __shared__ v4f sup4[NS * F4H];

    const v4f* sg = reinterpret_cast<const v4f*>(data + (size_t)c * NS * D);
    const float K = 2.88539008177792681472f;   // 2*log2(e); tanh(x)=1-2/(exp2(Kx)+1)
    const int q0 = qt * QPB + wave * 2;
    const v4f* qg0 = reinterpret_cast<const v4f*>(data + (size_t)(NC * NS + q0) * D);
    const v4f* qg1 = qg0 + 256;   // next query row

    // queries, pre-scaled by K (pk muls)
    v4f qa[4], qb[4];
    #pragma unroll
    for (int j = 0; j < 4; ++j) {
        qa[j] = qg0[lane + 64 * j] * K;
        qb[j] = qg1[lane + 64 * j] * K;
    }

    // ---- stage d-half 0 ----
    #pragma unroll
    for (int i = 0; i < 8; ++i) {
        int idx = tid + 256 * i;
        sup4[idx] = sg[((idx >> 7) << 8) + (idx & 127)];
    }
    __syncthreads();

    // ---- partial scores over d-half 0 ----
    float sc0[NS], sc1[NS];
    #pragma unroll
    for (int s = 0; s < NS; ++s) {
        v2f a0 = 0.f, a1 = 0.f;
        #pragma unroll
        for (int jj = 0; jj < 2; ++jj) {
            v4f sv = sup4[s * F4H + lane + 64 * jj];
            a0 += quad_term(sv.xy * qa[jj].xy, sv.zw * qa[jj].zw);
            a1 += quad_term(sv.xy * qb[jj].xy, sv.zw * qb[jj].zw);
        }
        sc0[s] = a0.x + a0.y;   // collapse to scalar: keeps reg footprint low
        sc1[s] = a1.x + a1.y;
    }
    __syncthreads();   // all waves done reading half 0

    // ---- stage d-half 1, finish scores ----
    #pragma unroll
    for (int i = 0; i < 8; ++i) {
        int idx = tid + 256 * i;
        sup4[idx] = sg[((idx >> 7) << 8) + 128 + (idx & 127)];
    }
    __syncthreads();

    #pragma unroll
    for (int s = 0; s < NS; ++s) {
        v2f a0 = 0.f, a1 = 0.f;
        #pragma unroll
        for (int jj = 0; jj < 2; ++jj) {
            v4f sv = sup4[s * F4H + lane + 64 * jj];
            a0 += quad_term(sv.xy * qa[2 + jj].xy, sv.zw * qa[2 + jj].zw);
            a1 += quad_term(sv.xy * qb[2 + jj].xy, sv.zw * qb[2 + jj].zw);
        }
        sc0[s] += a0.x + a0.y;
        sc1[s] += a1.x + a1.y;
    }

    // ---- wave64 butterfly reduction: sc[q][s] = D - 2*sum_d 1/(exp2+1) ----
    #pragma unroll
    for (int s = 0; s < NS; ++s) {
        float r0 = sc0[s], r1 = sc1[s];
        #pragma unroll
        for (int m = 32; m >= 1; m >>= 1) {
            r0 += __shfl_xor(r0, m, 64);
            r1 += __shfl_xor(r1, m, 64);
        }
        sc0[s] = (float)D - 2.f * r0;
        sc1[s] = (float)D - 2.f * r1;
    }

    // ---- softmax over s (16 values, replicated in every lane) ----
    const float L2E = 1.44269504088896340736f;
    float m0 = sc0[0], m1 = sc1[0];
    #pragma unroll
    for (int s = 1; s < NS; ++s) { m0 = fmaxf(m0, sc0[s]); m1 = fmaxf(m1, sc1[s]); }
    float sum0 = 0.f, sum1 = 0.f;
    #pragma unroll
    for (int s = 0; s < NS; ++s) {
        sc0[s] = __builtin_amdgcn_exp2f((sc0[s] - m0) * L2E);
        sc1[s] = __builtin_amdgcn_exp2f((sc1[s] - m1) * L2E);
        sum0 += sc0[s];
        sum1 += sc1[s];
    }
    const float inv0 = __builtin_amdgcn_rcpf(sum0);
    const float inv1 = __builtin_amdgcn_rcpf(sum1);
    #pragma unroll
    for (int s = 0; s < NS; ++s) { sc0[s] *= inv0; sc1[s] *= inv1; }

    v4f* og0 = reinterpret_cast<v4f*>(out + ((size_t)q0 * NC + c) * D);
    v4f* og1 = reinterpret_cast<v4f*>(out + ((size_t)(q0 + 1) * NC + c) * D);

    // ---- proto over d-half 1 (currently staged), packed FMAs ----
    {
        v2f o0xy[2], o0zw[2], o1xy[2], o1zw[2];
        #pragma unroll
        for (int jj = 0; jj < 2; ++jj) {
            o0xy[jj] = 0.f; o0zw[jj] = 0.f; o1xy[jj] = 0.f; o1zw[jj] = 0.f;
        }
        #pragma unroll
        for (int s = 0; s < NS; ++s) {
            const float a0 = sc0[s], a1 = sc1[s];
            #pragma unroll
            for (int jj = 0; jj < 2; ++jj) {
                v4f sv = sup4[s * F4H + lane + 64 * jj];
                o0xy[jj] += sv.xy * a0;   // v_pk_fma_f32
                o0zw[jj] += sv.zw * a0;
                o1xy[jj] += sv.xy * a1;
                o1zw[jj] += sv.zw * a1;
            }
        }
        #pragma unroll
        for (int jj = 0; jj < 2; ++jj) {
            v4f r0, r1;
            r0.xy = o0xy[jj]; r0.zw = o0zw[jj];
            r1.xy = o1xy[jj]; r1.zw = o1zw[jj];
            og0[128 + lane + 64 * jj] = r0;
            og1[128 + lane + 64 * jj] = r1;
        }
    }
    __syncthreads();   // all waves done reading half 1

    // ---- restage d-half 0, proto, store ----
    #pragma unroll
    for (int i = 0; i < 8; ++i) {
        int idx = tid + 256 * i;
        sup4[idx] = sg[((idx >> 7) << 8) + (idx & 127)];
    }
    __syncthreads();
    {
        v2f o0xy[2], o0zw[2], o1xy[2], o1zw[2];
        #pragma unroll
        for (int jj = 0; jj < 2; ++jj) {
            o0xy[jj] = 0.f; o0zw[jj] = 0.f; o1xy[jj] = 0.f; o1zw[jj] = 0.f;
        }
        #pragma unroll
        for (int s = 0; s < NS; ++s) {
            const float a0 = sc0[s], a1 = sc1[s];
            #pragma unroll
            for (int jj = 0; jj < 2; ++jj) {
                v4f sv = sup4[s * F4H + lane + 64 * jj];
                o0xy[jj] += sv.xy * a0;
                o0zw[jj] += sv.zw * a0;
                o1xy[jj] += sv.xy * a1;
                o1zw[jj] += sv.zw * a1;
            }
        }
        #pragma unroll
        for (int jj = 0; jj < 2; ++jj) {
            v4f r0, r1;
            r0.xy = o0xy[jj]; r0.zw = o0zw[jj];
            r1.xy = o1xy[jj]; r1.zw = o1zw[jj];
            og0[lane + 64 * jj] = r0;
            og1[lane + 64 * jj] = r1;
        }
    }
}

extern "C" void kernel_launch(void* const* d_in, const int* in_sizes, int n_in,
                              void* d_out, int out_size, void* d_ws, size_t ws_size,
                              hipStream_t stream) {
    (void)in_sizes; (void)n_in; (void)out_size; (void)d_ws; (void)ws_size;
    const float* data = (const float*)d_in[0];
    float* out = (float*)d_out;
    dim3 grid(NC, NQ / QPB);   // 32 classes x 64 query tiles = 2048 blocks
    proto_attn_kernel<<<grid, dim3(256), 0, stream>>>(data, out);
}